// Round 1
// baseline (510.297 us; speedup 1.0000x reference)
//
#include <hip/hip_runtime.h>

#define DIM 128

// ---------------- CSR build ----------------

__global__ void count_deg_kernel(const int* __restrict__ dst, int* __restrict__ deg, int E) {
    int e = blockIdx.x * blockDim.x + threadIdx.x;
    if (e < E) atomicAdd(&deg[dst[e]], 1);
}

// Single-block exclusive scan over n degrees (stored in offs[0..n-1]).
// Writes exclusive prefix to offs[i] and cursor[i]; offs[n] = total.
__global__ __launch_bounds__(1024) void scan_kernel(int* __restrict__ offs,
                                                    int* __restrict__ cursor, int n) {
    __shared__ int wsums[16];
    __shared__ int s_carry;
    int tid  = threadIdx.x;
    int lane = tid & 63;
    int w    = tid >> 6;
    if (tid == 0) s_carry = 0;
    __syncthreads();
    for (int base = 0; base < n; base += 1024) {
        int i = base + tid;
        int v = (i < n) ? offs[i] : 0;
        int s = v;
        #pragma unroll
        for (int o = 1; o < 64; o <<= 1) {
            int t = __shfl_up(s, o, 64);
            if (lane >= o) s += t;
        }
        if (lane == 63) wsums[w] = s;
        __syncthreads();
        if (w == 0) {
            int x = (lane < 16) ? wsums[lane] : 0;
            #pragma unroll
            for (int o = 1; o < 16; o <<= 1) {
                int t = __shfl_up(x, o, 64);
                if (lane >= o) x += t;
            }
            if (lane < 16) wsums[lane] = x;
        }
        __syncthreads();
        int wprefix = (w == 0) ? 0 : wsums[w - 1];
        int carry   = s_carry;
        int excl    = carry + wprefix + (s - v);
        if (i < n) { offs[i] = excl; cursor[i] = excl; }
        __syncthreads();                 // all reads of s_carry/wsums complete
        if (tid == 1023) s_carry = carry + wsums[15];
        __syncthreads();
    }
    if (threadIdx.x == 0) offs[n] = s_carry;
}

__global__ void scatter_kernel(const int* __restrict__ src, const int* __restrict__ dst,
                               const float* __restrict__ norm, int* __restrict__ cursor,
                               int* __restrict__ srcs_s, float* __restrict__ norms_s, int E) {
    int e = blockIdx.x * blockDim.x + threadIdx.x;
    if (e < E) {
        int d   = dst[e];
        int pos = atomicAdd(&cursor[d], 1);
        srcs_s[pos]  = src[e];
        norms_s[pos] = norm[e];
    }
}

// ---------------- GEMM: C[n][128] = A[n][128] * W[128][128]^T ----------------
// Block tile 64 rows x 128 cols, 256 threads, each thread 4x8 outputs.
// W staged transposed in LDS (Wt[k][j] = W[j][k]) so B-reads are float4.

__global__ __launch_bounds__(256) void gemm_xwt(const float* __restrict__ A,
                                                const float* __restrict__ W,
                                                float* __restrict__ C, int n) {
    __shared__ float As[64][132];    // +4 pad keeps 16B alignment, breaks conflicts
    __shared__ float Wt[128][132];
    int tid  = threadIdx.x;
    int row0 = blockIdx.x * 64;

    // stage W transposed
    #pragma unroll
    for (int base = 0; base < 128 * 128; base += 256 * 4) {
        int linear = base + tid * 4;
        int r = linear >> 7;      // output col j
        int c = linear & 127;     // k
        float4 wv = *(const float4*)(W + linear);
        Wt[c + 0][r] = wv.x; Wt[c + 1][r] = wv.y;
        Wt[c + 2][r] = wv.z; Wt[c + 3][r] = wv.w;
    }
    // stage A tile
    #pragma unroll
    for (int base = 0; base < 64 * 128; base += 256 * 4) {
        int linear = base + tid * 4;
        int r = linear >> 7;
        int c = linear & 127;
        int gr = row0 + r;
        float4 av = make_float4(0.f, 0.f, 0.f, 0.f);
        if (gr < n) av = *(const float4*)(A + (size_t)gr * DIM + c);
        *(float4*)&As[r][c] = av;
    }
    __syncthreads();

    int tx = tid & 15, ty = tid >> 4;   // cols: {tx*4..+3} and {64+tx*4..+3}
    float acc[4][8] = {};
    for (int k = 0; k < 128; k++) {
        float a0 = As[ty * 4 + 0][k];
        float a1 = As[ty * 4 + 1][k];
        float a2 = As[ty * 4 + 2][k];
        float a3 = As[ty * 4 + 3][k];
        float4 b0 = *(float4*)&Wt[k][tx * 4];
        float4 b1 = *(float4*)&Wt[k][64 + tx * 4];
        float as_[4] = {a0, a1, a2, a3};
        float bs[8]  = {b0.x, b0.y, b0.z, b0.w, b1.x, b1.y, b1.z, b1.w};
        #pragma unroll
        for (int i = 0; i < 4; i++) {
            #pragma unroll
            for (int j = 0; j < 8; j++) acc[i][j] += as_[i] * bs[j];
        }
    }

    #pragma unroll
    for (int i = 0; i < 4; i++) {
        int gr = row0 + ty * 4 + i;
        if (gr < n) {
            float4 o0 = make_float4(acc[i][0], acc[i][1], acc[i][2], acc[i][3]);
            float4 o1 = make_float4(acc[i][4], acc[i][5], acc[i][6], acc[i][7]);
            *(float4*)(C + (size_t)gr * DIM + tx * 4)      = o0;
            *(float4*)(C + (size_t)gr * DIM + 64 + tx * 4) = o1;
        }
    }
}

// ---------------- Propagate: out[node] = sum_{e: dst=node} S[src[e]] * norm[e] --------
// One wave per node; lane handles 2 floats (128 / 64). No atomics, full row write.

__global__ __launch_bounds__(256) void propagate_kernel(const float* __restrict__ S,
                                                        const int* __restrict__ offs,
                                                        const int* __restrict__ srcs_s,
                                                        const float* __restrict__ norms_s,
                                                        float* __restrict__ out,
                                                        int n, int do_relu) {
    int node = blockIdx.x * 4 + (threadIdx.x >> 6);
    if (node >= n) return;
    int lane = threadIdx.x & 63;
    int beg = offs[node];
    int end = offs[node + 1];
    float ax = 0.f, ay = 0.f;
    for (int i = beg; i < end; i++) {
        int   s  = srcs_s[i];
        float nv = norms_s[i];
        float2 v = *((const float2*)(S + (size_t)s * DIM) + lane);
        ax += nv * v.x;
        ay += nv * v.y;
    }
    if (do_relu) { ax = fmaxf(ax, 0.f); ay = fmaxf(ay, 0.f); }
    *((float2*)(out + (size_t)node * DIM) + lane) = make_float2(ax, ay);
}

// ---------------- launch ----------------

extern "C" void kernel_launch(void* const* d_in, const int* in_sizes, int n_in,
                              void* d_out, int out_size, void* d_ws, size_t ws_size,
                              hipStream_t stream) {
    const float* X    = (const float*)d_in[0];
    const float* W0   = (const float*)d_in[1];
    const float* W1   = (const float*)d_in[2];
    const float* norm = (const float*)d_in[3];
    const int*   src  = (const int*)d_in[4];
    const int*   dst  = (const int*)d_in[5];

    const int N = in_sizes[0] / DIM;   // 50000
    const int E = in_sizes[3];         // 800000

    float* Z = (float*)d_out;                       // first output chunk
    float* H = (float*)d_out + (size_t)N * DIM;     // second output chunk

    // workspace layout
    char* ws = (char*)d_ws;
    float* S       = (float*)ws;                        // N*DIM f32 = 25.6 MB
    size_t off     = (size_t)N * DIM * sizeof(float);
    int*   offs    = (int*)(ws + off); off += ((size_t)(N + 1) * 4 + 255) / 256 * 256;
    int*   cursor  = (int*)(ws + off); off += ((size_t)N * 4 + 255) / 256 * 256;
    int*   srcs_s  = (int*)(ws + off); off += (size_t)E * 4;
    float* norms_s = (float*)(ws + off); off += (size_t)E * 4;

    // ---- CSR build (same graph used for both propagates) ----
    hipMemsetAsync(offs, 0, (size_t)(N + 1) * sizeof(int), stream);
    count_deg_kernel<<<(E + 255) / 256, 256, 0, stream>>>(dst, offs, E);
    scan_kernel<<<1, 1024, 0, stream>>>(offs, cursor, N);
    scatter_kernel<<<(E + 255) / 256, 256, 0, stream>>>(src, dst, norm, cursor,
                                                        srcs_s, norms_s, E);

    const int gemm_grid = (N + 63) / 64;
    const int prop_grid = (N + 3) / 4;

    // ---- layer 1 ----
    gemm_xwt<<<gemm_grid, 256, 0, stream>>>(X, W0, S, N);
    propagate_kernel<<<prop_grid, 256, 0, stream>>>(S, offs, srcs_s, norms_s, H, N, 1);

    // ---- layer 2 ----
    gemm_xwt<<<gemm_grid, 256, 0, stream>>>(H, W1, S, N);
    propagate_kernel<<<prop_grid, 256, 0, stream>>>(S, offs, srcs_s, norms_s, Z, N, 0);
}

// Round 2
// 397.664 us; speedup vs baseline: 1.2832x; 1.2832x over previous
//
#include <hip/hip_runtime.h>

#define DIM 128

// ---------------- CSR build ----------------

__global__ void count_deg_kernel(const int* __restrict__ dst, int* __restrict__ deg, int E) {
    int e = blockIdx.x * blockDim.x + threadIdx.x;
    if (e < E) atomicAdd(&deg[dst[e]], 1);
}

// ---- multi-block exclusive scan over deg[0..n-1] (deg lives in `cursor`) ----
// part1: per-block (256) sums -> bsums[blk]
__global__ __launch_bounds__(256) void scan_part1(const int* __restrict__ deg,
                                                  int* __restrict__ bsums, int n) {
    __shared__ int ws_[4];
    int i = blockIdx.x * 256 + threadIdx.x;
    int v = (i < n) ? deg[i] : 0;
    int lane = threadIdx.x & 63, w = threadIdx.x >> 6;
    int s = v;
    #pragma unroll
    for (int o = 1; o < 64; o <<= 1) { int t = __shfl_up(s, o, 64); if (lane >= o) s += t; }
    if (lane == 63) ws_[w] = s;
    __syncthreads();
    if (threadIdx.x == 0) bsums[blockIdx.x] = ws_[0] + ws_[1] + ws_[2] + ws_[3];
}

// part2: single block exclusive-scans nb (<=256) block sums in place; offs[n] = total
__global__ __launch_bounds__(256) void scan_part2(int* __restrict__ bsums,
                                                  int* __restrict__ offs, int nb, int n) {
    __shared__ int ws_[4];
    int t = threadIdx.x;
    int v = (t < nb) ? bsums[t] : 0;
    int lane = t & 63, w = t >> 6;
    int s = v;
    #pragma unroll
    for (int o = 1; o < 64; o <<= 1) { int x = __shfl_up(s, o, 64); if (lane >= o) s += x; }
    if (lane == 63) ws_[w] = s;
    __syncthreads();
    int wpref = 0;
    for (int k = 0; k < w; k++) wpref += ws_[k];
    int incl = wpref + s;
    int excl = incl - v;
    if (t < nb) bsums[t] = excl;
    if (t == 255) offs[n] = incl;   // lanes beyond nb contributed 0
}

// part3: recompute intra-block exclusive scan of deg, add bsums[blk] -> offs, cursor
__global__ __launch_bounds__(256) void scan_part3(const int* __restrict__ bsums,
                                                  int* __restrict__ deg_and_cursor,
                                                  int* __restrict__ offs, int n) {
    __shared__ int ws_[4];
    int i = blockIdx.x * 256 + threadIdx.x;
    int v = (i < n) ? deg_and_cursor[i] : 0;
    int lane = threadIdx.x & 63, w = threadIdx.x >> 6;
    int s = v;
    #pragma unroll
    for (int o = 1; o < 64; o <<= 1) { int t = __shfl_up(s, o, 64); if (lane >= o) s += t; }
    if (lane == 63) ws_[w] = s;
    __syncthreads();
    int wpref = 0;
    for (int k = 0; k < w; k++) wpref += ws_[k];
    int excl = bsums[blockIdx.x] + wpref + (s - v);
    if (i < n) { offs[i] = excl; deg_and_cursor[i] = excl; }  // cursor = offs copy
}

__global__ void scatter_kernel(const int* __restrict__ src, const int* __restrict__ dst,
                               const float* __restrict__ norm, int* __restrict__ cursor,
                               int2* __restrict__ edges, int E) {
    int e = blockIdx.x * blockDim.x + threadIdx.x;
    if (e < E) {
        int d   = dst[e];
        int pos = atomicAdd(&cursor[d], 1);
        edges[pos] = make_int2(src[e], __float_as_int(norm[e]));
    }
}

// ---------------- GEMM: C[n][128] = A[n][128] * W[128][128]^T ----------------

__global__ __launch_bounds__(256) void gemm_xwt(const float* __restrict__ A,
                                                const float* __restrict__ W,
                                                float* __restrict__ C, int n) {
    __shared__ float As[64][132];
    __shared__ float Wt[128][132];
    int tid  = threadIdx.x;
    int row0 = blockIdx.x * 64;

    #pragma unroll
    for (int base = 0; base < 128 * 128; base += 256 * 4) {
        int linear = base + tid * 4;
        int r = linear >> 7;      // output col j
        int c = linear & 127;     // k
        float4 wv = *(const float4*)(W + linear);
        Wt[c + 0][r] = wv.x; Wt[c + 1][r] = wv.y;
        Wt[c + 2][r] = wv.z; Wt[c + 3][r] = wv.w;
    }
    #pragma unroll
    for (int base = 0; base < 64 * 128; base += 256 * 4) {
        int linear = base + tid * 4;
        int r = linear >> 7;
        int c = linear & 127;
        int gr = row0 + r;
        float4 av = make_float4(0.f, 0.f, 0.f, 0.f);
        if (gr < n) av = *(const float4*)(A + (size_t)gr * DIM + c);
        *(float4*)&As[r][c] = av;
    }
    __syncthreads();

    int tx = tid & 15, ty = tid >> 4;
    float acc[4][8] = {};
    for (int k = 0; k < 128; k++) {
        float a0 = As[ty * 4 + 0][k];
        float a1 = As[ty * 4 + 1][k];
        float a2 = As[ty * 4 + 2][k];
        float a3 = As[ty * 4 + 3][k];
        float4 b0 = *(float4*)&Wt[k][tx * 4];
        float4 b1 = *(float4*)&Wt[k][64 + tx * 4];
        float as_[4] = {a0, a1, a2, a3};
        float bs[8]  = {b0.x, b0.y, b0.z, b0.w, b1.x, b1.y, b1.z, b1.w};
        #pragma unroll
        for (int i = 0; i < 4; i++) {
            #pragma unroll
            for (int j = 0; j < 8; j++) acc[i][j] += as_[i] * bs[j];
        }
    }

    #pragma unroll
    for (int i = 0; i < 4; i++) {
        int gr = row0 + ty * 4 + i;
        if (gr < n) {
            float4 o0 = make_float4(acc[i][0], acc[i][1], acc[i][2], acc[i][3]);
            float4 o1 = make_float4(acc[i][4], acc[i][5], acc[i][6], acc[i][7]);
            *(float4*)(C + (size_t)gr * DIM + tx * 4)      = o0;
            *(float4*)(C + (size_t)gr * DIM + 64 + tx * 4) = o1;
        }
    }
}

// ---------------- Propagate ----------------
// One wave per node. 32 lanes cover the 128-float row as float4; the two
// half-waves process even/odd edges concurrently; 2x manual unroll per half
// -> 4 row-gathers in flight per wave. Halves combined via shfl_xor(32).

__global__ __launch_bounds__(256) void propagate_kernel(const float* __restrict__ S,
                                                        const int* __restrict__ offs,
                                                        const int2* __restrict__ edges,
                                                        float* __restrict__ out,
                                                        int n, int do_relu) {
    int node = blockIdx.x * 4 + (threadIdx.x >> 6);
    if (node >= n) return;
    int lane = threadIdx.x & 63;
    int half = lane >> 5;
    int l32  = lane & 31;
    int beg = offs[node];
    int end = offs[node + 1];
    float ax = 0.f, ay = 0.f, az = 0.f, aw = 0.f;
    int i = beg + half;
    for (; i + 2 < end; i += 4) {
        int2 e0 = edges[i];
        int2 e1 = edges[i + 2];
        float4 v0 = *((const float4*)(S + (size_t)e0.x * DIM) + l32);
        float4 v1 = *((const float4*)(S + (size_t)e1.x * DIM) + l32);
        float n0 = __int_as_float(e0.y);
        float n1 = __int_as_float(e1.y);
        ax += n0 * v0.x; ay += n0 * v0.y; az += n0 * v0.z; aw += n0 * v0.w;
        ax += n1 * v1.x; ay += n1 * v1.y; az += n1 * v1.z; aw += n1 * v1.w;
    }
    for (; i < end; i += 2) {
        int2 e = edges[i];
        float4 v = *((const float4*)(S + (size_t)e.x * DIM) + l32);
        float nv = __int_as_float(e.y);
        ax += nv * v.x; ay += nv * v.y; az += nv * v.z; aw += nv * v.w;
    }
    ax += __shfl_xor(ax, 32, 64);
    ay += __shfl_xor(ay, 32, 64);
    az += __shfl_xor(az, 32, 64);
    aw += __shfl_xor(aw, 32, 64);
    if (half == 0) {
        if (do_relu) {
            ax = fmaxf(ax, 0.f); ay = fmaxf(ay, 0.f);
            az = fmaxf(az, 0.f); aw = fmaxf(aw, 0.f);
        }
        *((float4*)(out + (size_t)node * DIM) + l32) = make_float4(ax, ay, az, aw);
    }
}

// ---------------- launch ----------------

extern "C" void kernel_launch(void* const* d_in, const int* in_sizes, int n_in,
                              void* d_out, int out_size, void* d_ws, size_t ws_size,
                              hipStream_t stream) {
    const float* X    = (const float*)d_in[0];
    const float* W0   = (const float*)d_in[1];
    const float* W1   = (const float*)d_in[2];
    const float* norm = (const float*)d_in[3];
    const int*   src  = (const int*)d_in[4];
    const int*   dst  = (const int*)d_in[5];

    const int N = in_sizes[0] / DIM;   // 50000
    const int E = in_sizes[3];         // 800000

    float* Z = (float*)d_out;
    float* H = (float*)d_out + (size_t)N * DIM;

    // workspace layout (~32.4 MB)
    char* ws = (char*)d_ws;
    float* S      = (float*)ws;
    size_t off    = (size_t)N * DIM * sizeof(float);
    int*   offs   = (int*)(ws + off); off += ((size_t)(N + 1) * 4 + 255) / 256 * 256;
    int*   cursor = (int*)(ws + off); off += ((size_t)N * 4 + 255) / 256 * 256;  // deg, then cursor
    int*   bsums  = (int*)(ws + off); off += 1024;
    int2*  edges  = (int2*)(ws + off); off += (size_t)E * 8;

    const int nb = (N + 255) / 256;    // 196 blocks (<=256 required by scan_part2)

    // ---- CSR build ----
    hipMemsetAsync(cursor, 0, (size_t)N * sizeof(int), stream);
    count_deg_kernel<<<(E + 255) / 256, 256, 0, stream>>>(dst, cursor, E);
    scan_part1<<<nb, 256, 0, stream>>>(cursor, bsums, N);
    scan_part2<<<1, 256, 0, stream>>>(bsums, offs, nb, N);
    scan_part3<<<nb, 256, 0, stream>>>(bsums, cursor, offs, N);
    scatter_kernel<<<(E + 255) / 256, 256, 0, stream>>>(src, dst, norm, cursor, edges, E);

    const int gemm_grid = (N + 63) / 64;
    const int prop_grid = (N + 3) / 4;

    // ---- layer 1 ----
    gemm_xwt<<<gemm_grid, 256, 0, stream>>>(X, W0, S, N);
    propagate_kernel<<<prop_grid, 256, 0, stream>>>(S, offs, edges, H, N, 1);

    // ---- layer 2 ----
    gemm_xwt<<<gemm_grid, 256, 0, stream>>>(H, W1, S, N);
    propagate_kernel<<<prop_grid, 256, 0, stream>>>(S, offs, edges, Z, N, 0);
}

// Round 3
// 283.489 us; speedup vs baseline: 1.8001x; 1.4028x over previous
//
#include <hip/hip_runtime.h>

#define DIM 128

typedef __attribute__((ext_vector_type(8))) short bf16x8_t;
typedef __attribute__((ext_vector_type(4))) float f32x4_t;

__device__ __forceinline__ short f2bf(float f) {
    unsigned u = __float_as_uint(f);
    u += 0x7FFFu + ((u >> 16) & 1u);        // round-to-nearest-even
    return (short)(u >> 16);
}
__device__ __forceinline__ float bf2f(short s) {
    return __uint_as_float(((unsigned)(unsigned short)s) << 16);
}

// ---------------- f32 -> bf16 convert (for W0/W1) ----------------
__global__ void cvt_f32_bf16(const float* __restrict__ in, short* __restrict__ out, int n) {
    int i = (blockIdx.x * 256 + threadIdx.x) * 8;
    if (i < n) {
        float4 a = *(const float4*)(in + i);
        float4 b = *(const float4*)(in + i + 4);
        bf16x8_t o;
        o[0] = f2bf(a.x); o[1] = f2bf(a.y); o[2] = f2bf(a.z); o[3] = f2bf(a.w);
        o[4] = f2bf(b.x); o[5] = f2bf(b.y); o[6] = f2bf(b.z); o[7] = f2bf(b.w);
        *(bf16x8_t*)(out + i) = o;
    }
}

// ---------------- CSR build ----------------

__global__ void count_deg_kernel(const int* __restrict__ dst, int* __restrict__ deg, int E) {
    int e = blockIdx.x * blockDim.x + threadIdx.x;
    if (e < E) atomicAdd(&deg[dst[e]], 1);
}

__global__ __launch_bounds__(256) void scan_part1(const int* __restrict__ deg,
                                                  int* __restrict__ bsums, int n) {
    __shared__ int ws_[4];
    int i = blockIdx.x * 256 + threadIdx.x;
    int v = (i < n) ? deg[i] : 0;
    int lane = threadIdx.x & 63, w = threadIdx.x >> 6;
    int s = v;
    #pragma unroll
    for (int o = 1; o < 64; o <<= 1) { int t = __shfl_up(s, o, 64); if (lane >= o) s += t; }
    if (lane == 63) ws_[w] = s;
    __syncthreads();
    if (threadIdx.x == 0) bsums[blockIdx.x] = ws_[0] + ws_[1] + ws_[2] + ws_[3];
}

__global__ __launch_bounds__(256) void scan_part2(int* __restrict__ bsums,
                                                  int* __restrict__ offs, int nb, int n) {
    __shared__ int ws_[4];
    int t = threadIdx.x;
    int v = (t < nb) ? bsums[t] : 0;
    int lane = t & 63, w = t >> 6;
    int s = v;
    #pragma unroll
    for (int o = 1; o < 64; o <<= 1) { int x = __shfl_up(s, o, 64); if (lane >= o) s += x; }
    if (lane == 63) ws_[w] = s;
    __syncthreads();
    int wpref = 0;
    for (int k = 0; k < w; k++) wpref += ws_[k];
    int incl = wpref + s;
    int excl = incl - v;
    if (t < nb) bsums[t] = excl;
    if (t == 255) offs[n] = incl;
}

__global__ __launch_bounds__(256) void scan_part3(const int* __restrict__ bsums,
                                                  int* __restrict__ deg_and_cursor,
                                                  int* __restrict__ offs, int n) {
    __shared__ int ws_[4];
    int i = blockIdx.x * 256 + threadIdx.x;
    int v = (i < n) ? deg_and_cursor[i] : 0;
    int lane = threadIdx.x & 63, w = threadIdx.x >> 6;
    int s = v;
    #pragma unroll
    for (int o = 1; o < 64; o <<= 1) { int t = __shfl_up(s, o, 64); if (lane >= o) s += t; }
    if (lane == 63) ws_[w] = s;
    __syncthreads();
    int wpref = 0;
    for (int k = 0; k < w; k++) wpref += ws_[k];
    int excl = bsums[blockIdx.x] + wpref + (s - v);
    if (i < n) { offs[i] = excl; deg_and_cursor[i] = excl; }
}

__global__ void scatter_kernel(const int* __restrict__ src, const int* __restrict__ dst,
                               const float* __restrict__ norm, int* __restrict__ cursor,
                               int2* __restrict__ edges, int E) {
    int e = blockIdx.x * blockDim.x + threadIdx.x;
    if (e < E) {
        int d   = dst[e];
        int pos = atomicAdd(&cursor[d], 1);
        edges[pos] = make_int2(src[e], __float_as_int(norm[e]));
    }
}

// ---------------- GEMM (bf16 MFMA): Cbf[n][128] = bf16( A[n][128] @ Wbf[128][128]^T )
// No LDS. A-frag = 8 consecutive f32 from an A row (cvt inline); B-frag = 8
// consecutive bf16 from a W row (W stored [out][in], exactly the B[k][n] frag).
// 4 waves/block, 16 rows/wave, 8 col-tiles x 4 k-chunks of 16x16x32 MFMA.

__global__ __launch_bounds__(256) void gemm_mfma(const float* __restrict__ A,
                                                 const short* __restrict__ Wbf,
                                                 short* __restrict__ Cbf, int n) {
    int wave = threadIdx.x >> 6;
    int lane = threadIdx.x & 63;
    int l16  = lane & 15;
    int quad = lane >> 4;
    int r0 = blockIdx.x * 64 + wave * 16;

    int arow = r0 + l16;
    if (arow >= n) arow = n - 1;               // clamp: OOB rows never stored
    const float* Ar = A + (size_t)arow * DIM + quad * 8;

    bf16x8_t fa[4];
    #pragma unroll
    for (int kk = 0; kk < 4; kk++) {
        float4 x0 = *(const float4*)(Ar + kk * 32);
        float4 x1 = *(const float4*)(Ar + kk * 32 + 4);
        bf16x8_t f;
        f[0] = f2bf(x0.x); f[1] = f2bf(x0.y); f[2] = f2bf(x0.z); f[3] = f2bf(x0.w);
        f[4] = f2bf(x1.x); f[5] = f2bf(x1.y); f[6] = f2bf(x1.z); f[7] = f2bf(x1.w);
        fa[kk] = f;
    }

    #pragma unroll
    for (int ct = 0; ct < 8; ct++) {
        const short* Wr = Wbf + (size_t)(ct * 16 + l16) * DIM + quad * 8;
        f32x4_t acc = {0.f, 0.f, 0.f, 0.f};
        #pragma unroll
        for (int kk = 0; kk < 4; kk++) {
            bf16x8_t fb = *(const bf16x8_t*)(Wr + kk * 32);
            acc = __builtin_amdgcn_mfma_f32_16x16x32_bf16(fa[kk], fb, acc, 0, 0, 0);
        }
        #pragma unroll
        for (int j = 0; j < 4; j++) {
            int row = r0 + quad * 4 + j;
            if (row < n) Cbf[(size_t)row * DIM + ct * 16 + l16] = f2bf(acc[j]);
        }
    }
}

// ---------------- Propagate: out[v] = sum_{e: dst=v} Sbf[src[e]] * norm[e]
// One wave per node; quarter-wave (16 lanes) covers a full 256B bf16 row
// (8 bf16/lane). Quarters process edge streams beg+q step 4, unroll 2
// -> 8 gathers in flight per wave. f32 accumulate, shfl-reduce quarters.

__global__ __launch_bounds__(256) void propagate_kernel(const short* __restrict__ Sbf,
                                                        const int* __restrict__ offs,
                                                        const int2* __restrict__ edges,
                                                        float* __restrict__ out,
                                                        int n, int do_relu) {
    int node = blockIdx.x * 4 + (threadIdx.x >> 6);
    if (node >= n) return;
    int lane = threadIdx.x & 63;
    int q   = lane >> 4;
    int l16 = lane & 15;
    int beg = offs[node];
    int end = offs[node + 1];

    float acc[8] = {};
    int i = beg + q;
    for (; i + 4 < end; i += 8) {
        int2 e0 = edges[i];
        int2 e1 = edges[i + 4];
        bf16x8_t v0 = *(const bf16x8_t*)(Sbf + (size_t)e0.x * DIM + l16 * 8);
        bf16x8_t v1 = *(const bf16x8_t*)(Sbf + (size_t)e1.x * DIM + l16 * 8);
        float n0 = __int_as_float(e0.y);
        float n1 = __int_as_float(e1.y);
        #pragma unroll
        for (int j = 0; j < 8; j++) acc[j] += n0 * bf2f(v0[j]);
        #pragma unroll
        for (int j = 0; j < 8; j++) acc[j] += n1 * bf2f(v1[j]);
    }
    for (; i < end; i += 4) {
        int2 e = edges[i];
        bf16x8_t v = *(const bf16x8_t*)(Sbf + (size_t)e.x * DIM + l16 * 8);
        float nv = __int_as_float(e.y);
        #pragma unroll
        for (int j = 0; j < 8; j++) acc[j] += nv * bf2f(v[j]);
    }

    #pragma unroll
    for (int j = 0; j < 8; j++) {
        acc[j] += __shfl_xor(acc[j], 16, 64);
        acc[j] += __shfl_xor(acc[j], 32, 64);
    }
    if (q == 0) {
        if (do_relu) {
            #pragma unroll
            for (int j = 0; j < 8; j++) acc[j] = fmaxf(acc[j], 0.f);
        }
        float4 o0 = make_float4(acc[0], acc[1], acc[2], acc[3]);
        float4 o1 = make_float4(acc[4], acc[5], acc[6], acc[7]);
        float* row = out + (size_t)node * DIM + l16 * 8;
        *(float4*)row       = o0;
        *(float4*)(row + 4) = o1;
    }
}

// ---------------- launch ----------------

extern "C" void kernel_launch(void* const* d_in, const int* in_sizes, int n_in,
                              void* d_out, int out_size, void* d_ws, size_t ws_size,
                              hipStream_t stream) {
    const float* X    = (const float*)d_in[0];
    const float* W0   = (const float*)d_in[1];
    const float* W1   = (const float*)d_in[2];
    const float* norm = (const float*)d_in[3];
    const int*   src  = (const int*)d_in[4];
    const int*   dst  = (const int*)d_in[5];

    const int N = in_sizes[0] / DIM;   // 50000
    const int E = in_sizes[3];         // 800000

    float* Z = (float*)d_out;
    float* H = (float*)d_out + (size_t)N * DIM;

    // workspace layout (~19.5 MB)
    char* ws = (char*)d_ws;
    short* Sbf   = (short*)ws;                       // N*128 bf16 = 12.8 MB
    size_t off   = (size_t)N * DIM * sizeof(short);
    short* Wbf0  = (short*)(ws + off); off += DIM * DIM * sizeof(short);
    short* Wbf1  = (short*)(ws + off); off += DIM * DIM * sizeof(short);
    int*   offs  = (int*)(ws + off); off += ((size_t)(N + 1) * 4 + 255) / 256 * 256;
    int*   cursor= (int*)(ws + off); off += ((size_t)N * 4 + 255) / 256 * 256;
    int*   bsums = (int*)(ws + off); off += 1024;
    int2*  edges = (int2*)(ws + off); off += (size_t)E * 8;

    const int nb = (N + 255) / 256;    // 196 (<=256 for scan_part2)

    // ---- W -> bf16 (independent of CSR chain) ----
    cvt_f32_bf16<<<(DIM * DIM + 2047) / 2048, 256, 0, stream>>>(W0, Wbf0, DIM * DIM);
    cvt_f32_bf16<<<(DIM * DIM + 2047) / 2048, 256, 0, stream>>>(W1, Wbf1, DIM * DIM);

    // ---- CSR build ----
    hipMemsetAsync(cursor, 0, (size_t)N * sizeof(int), stream);
    count_deg_kernel<<<(E + 255) / 256, 256, 0, stream>>>(dst, cursor, E);
    scan_part1<<<nb, 256, 0, stream>>>(cursor, bsums, N);
    scan_part2<<<1, 256, 0, stream>>>(bsums, offs, nb, N);
    scan_part3<<<nb, 256, 0, stream>>>(bsums, cursor, offs, N);
    scatter_kernel<<<(E + 255) / 256, 256, 0, stream>>>(src, dst, norm, cursor, edges, E);

    const int gemm_grid = (N + 63) / 64;
    const int prop_grid = (N + 3) / 4;

    // ---- layer 1 ----
    gemm_mfma<<<gemm_grid, 256, 0, stream>>>(X, Wbf0, Sbf, N);
    propagate_kernel<<<prop_grid, 256, 0, stream>>>(Sbf, offs, edges, H, N, 1);

    // ---- layer 2 ----
    gemm_mfma<<<gemm_grid, 256, 0, stream>>>(H, Wbf1, Sbf, N);
    propagate_kernel<<<prop_grid, 256, 0, stream>>>(Sbf, offs, edges, Z, N, 0);
}

// Round 4
// 237.562 us; speedup vs baseline: 2.1481x; 1.1933x over previous
//
#include <hip/hip_runtime.h>

#define DIM 128
#define NB 196            // ceil(50000/256) dst-buckets of 256 nodes

typedef __attribute__((ext_vector_type(8))) short bf16x8_t;
typedef __attribute__((ext_vector_type(4))) float f32x4_t;

__device__ __forceinline__ short f2bf(float f) {
    unsigned u = __float_as_uint(f);
    u += 0x7FFFu + ((u >> 16) & 1u);        // round-to-nearest-even
    return (short)(u >> 16);
}
__device__ __forceinline__ float bf2f(short s) {
    return __uint_as_float(((unsigned)(unsigned short)s) << 16);
}

// ---------------- f32 -> bf16 convert (for W0/W1) ----------------
__global__ void cvt_f32_bf16(const float* __restrict__ in, short* __restrict__ out, int n) {
    int i = (blockIdx.x * 256 + threadIdx.x) * 8;
    if (i < n) {
        float4 a = *(const float4*)(in + i);
        float4 b = *(const float4*)(in + i + 4);
        bf16x8_t o;
        o[0] = f2bf(a.x); o[1] = f2bf(a.y); o[2] = f2bf(a.z); o[3] = f2bf(a.w);
        o[4] = f2bf(b.x); o[5] = f2bf(b.y); o[6] = f2bf(b.z); o[7] = f2bf(b.w);
        *(bf16x8_t*)(out + i) = o;
    }
}

// ---------------- CSR build: two-level bucket sort ----------------
// Stage 1: per-bucket counts (bucket = dst >> 8) via LDS histograms.
__global__ __launch_bounds__(256) void bucket_count(const int* __restrict__ dst,
                                                    int* __restrict__ bcount, int E) {
    __shared__ int hist[NB];
    int t = threadIdx.x;
    for (int b = t; b < NB; b += 256) hist[b] = 0;
    __syncthreads();
    int idx = (blockIdx.x * 256 + t) * 4;
    if (idx + 3 < E) {
        int4 d = *(const int4*)(dst + idx);
        atomicAdd(&hist[d.x >> 8], 1);
        atomicAdd(&hist[d.y >> 8], 1);
        atomicAdd(&hist[d.z >> 8], 1);
        atomicAdd(&hist[d.w >> 8], 1);
    } else {
        for (int k = idx; k < E; k++) atomicAdd(&hist[dst[k] >> 8], 1);
    }
    __syncthreads();
    for (int b = t; b < NB; b += 256) {
        int c = hist[b];
        if (c) atomicAdd(&bcount[b], c);
    }
}

// Stage 2: exclusive scan of NB (<256) bucket counts -> boffs[0..NB], bcursor.
__global__ __launch_bounds__(256) void bucket_scan(const int* __restrict__ bcount,
                                                   int* __restrict__ boffs,
                                                   int* __restrict__ bcursor) {
    __shared__ int ws_[4];
    int t = threadIdx.x;
    int v = (t < NB) ? bcount[t] : 0;
    int lane = t & 63, w = t >> 6;
    int s = v;
    #pragma unroll
    for (int o = 1; o < 64; o <<= 1) { int x = __shfl_up(s, o, 64); if (lane >= o) s += x; }
    if (lane == 63) ws_[w] = s;
    __syncthreads();
    int wpref = 0;
    for (int k = 0; k < w; k++) wpref += ws_[k];
    int incl = wpref + s;
    int excl = incl - v;
    if (t < NB) { boffs[t] = excl; bcursor[t] = excl; }
    if (t == 255) boffs[NB] = incl;
}

// Stage 3: bin edges into bucket regions. Each block claims one compact chunk
// per bucket (one atomic per bucket per block), so its stores land in its own
// ~32 KB footprint -> single-XCD lines, ~no writeback amplification.
// binned.x packs (dst&255)<<24 | src  (src < 2^24), binned.y = norm bits.
#define SC_VPT 16
__global__ __launch_bounds__(256) void bucket_scatter(const int* __restrict__ src,
                                                      const int* __restrict__ dst,
                                                      const float* __restrict__ norm,
                                                      int* __restrict__ bcursor,
                                                      int2* __restrict__ binned, int E) {
    __shared__ int hist[NB];
    __shared__ int base[NB];
    int t = threadIdx.x;
    for (int b = t; b < NB; b += 256) hist[b] = 0;
    __syncthreads();

    int e0 = blockIdx.x * (256 * SC_VPT);
    int bkts[SC_VPT];
    int pack[SC_VPT];
    int nrm[SC_VPT];
    #pragma unroll
    for (int k = 0; k < SC_VPT; k++) {
        int e = e0 + k * 256 + t;               // coalesced strided reads
        if (e < E) {
            int d = dst[e];
            bkts[k] = d >> 8;
            pack[k] = ((d & 255) << 24) | src[e];
            nrm[k]  = __float_as_int(norm[e]);
            atomicAdd(&hist[bkts[k]], 1);
        } else bkts[k] = -1;
    }
    __syncthreads();
    for (int b = t; b < NB; b += 256) {
        int c = hist[b];
        base[b] = c ? atomicAdd(&bcursor[b], c) : 0;
        hist[b] = 0;
    }
    __syncthreads();
    #pragma unroll
    for (int k = 0; k < SC_VPT; k++) {
        if (bkts[k] >= 0) {
            int pos = base[bkts[k]] + atomicAdd(&hist[bkts[k]], 1);
            binned[pos] = make_int2(pack[k], nrm[k]);
        }
    }
}

// Stage 4: one block per bucket. Counting-sort the bucket's edges by dst&255
// (edges stay inside the bucket's L2-hot ~32 KB region), emit final CSR
// segment + per-node offs. Replaces the old global scan kernels.
__global__ __launch_bounds__(1024) void bucket_csr(const int2* __restrict__ binned,
                                                   const int* __restrict__ boffs,
                                                   int* __restrict__ offs,
                                                   int2* __restrict__ edges, int n) {
    __shared__ int hist[256];
    __shared__ int ws_[4];
    int b   = blockIdx.x;
    int beg = boffs[b];
    int end = boffs[b + 1];
    int t   = threadIdx.x;
    if (t < 256) hist[t] = 0;
    __syncthreads();
    for (int i = beg + t; i < end; i += 1024)
        atomicAdd(&hist[(unsigned)binned[i].x >> 24], 1);
    __syncthreads();
    // exclusive scan of hist[256] (threads 0..255 = 4 waves)
    int v = (t < 256) ? hist[t] : 0;
    int lane = t & 63, w = t >> 6;
    int s = v;
    #pragma unroll
    for (int o = 1; o < 64; o <<= 1) { int x = __shfl_up(s, o, 64); if (lane >= o) s += x; }
    if (t < 256 && lane == 63) ws_[w] = s;
    __syncthreads();
    int wpref = 0;
    if (t < 256) for (int k = 0; k < w; k++) wpref += ws_[k];
    int excl = wpref + s - v;
    __syncthreads();
    if (t < 256) {
        hist[t] = beg + excl;                   // becomes per-node cursor
        int idx = b * 256 + t;
        if (idx <= n) offs[idx] = beg + excl;   // idx==n -> beg+total == E
    }
    __syncthreads();
    for (int i = beg + t; i < end; i += 1024) {
        int2 pr = binned[i];
        unsigned p = (unsigned)pr.x;
        int pos = atomicAdd(&hist[p >> 24], 1);
        edges[pos] = make_int2((int)(p & 0xFFFFFF), pr.y);
    }
}

// ---------------- GEMM (bf16 MFMA): Cbf[n][128] = bf16( A[n][128] @ Wbf^T )

__global__ __launch_bounds__(256) void gemm_mfma(const float* __restrict__ A,
                                                 const short* __restrict__ Wbf,
                                                 short* __restrict__ Cbf, int n) {
    int wave = threadIdx.x >> 6;
    int lane = threadIdx.x & 63;
    int l16  = lane & 15;
    int quad = lane >> 4;
    int r0 = blockIdx.x * 64 + wave * 16;

    int arow = r0 + l16;
    if (arow >= n) arow = n - 1;               // clamp: OOB rows never stored
    const float* Ar = A + (size_t)arow * DIM + quad * 8;

    bf16x8_t fa[4];
    #pragma unroll
    for (int kk = 0; kk < 4; kk++) {
        float4 x0 = *(const float4*)(Ar + kk * 32);
        float4 x1 = *(const float4*)(Ar + kk * 32 + 4);
        bf16x8_t f;
        f[0] = f2bf(x0.x); f[1] = f2bf(x0.y); f[2] = f2bf(x0.z); f[3] = f2bf(x0.w);
        f[4] = f2bf(x1.x); f[5] = f2bf(x1.y); f[6] = f2bf(x1.z); f[7] = f2bf(x1.w);
        fa[kk] = f;
    }

    #pragma unroll
    for (int ct = 0; ct < 8; ct++) {
        const short* Wr = Wbf + (size_t)(ct * 16 + l16) * DIM + quad * 8;
        f32x4_t acc = {0.f, 0.f, 0.f, 0.f};
        #pragma unroll
        for (int kk = 0; kk < 4; kk++) {
            bf16x8_t fb = *(const bf16x8_t*)(Wr + kk * 32);
            acc = __builtin_amdgcn_mfma_f32_16x16x32_bf16(fa[kk], fb, acc, 0, 0, 0);
        }
        #pragma unroll
        for (int j = 0; j < 4; j++) {
            int row = r0 + quad * 4 + j;
            if (row < n) Cbf[(size_t)row * DIM + ct * 16 + l16] = f2bf(acc[j]);
        }
    }
}

// ---------------- Propagate: out[v] = sum_{e: dst=v} Sbf[src[e]] * norm[e]

__global__ __launch_bounds__(256) void propagate_kernel(const short* __restrict__ Sbf,
                                                        const int* __restrict__ offs,
                                                        const int2* __restrict__ edges,
                                                        float* __restrict__ out,
                                                        int n, int do_relu) {
    int node = blockIdx.x * 4 + (threadIdx.x >> 6);
    if (node >= n) return;
    int lane = threadIdx.x & 63;
    int q   = lane >> 4;
    int l16 = lane & 15;
    int beg = offs[node];
    int end = offs[node + 1];

    float acc[8] = {};
    int i = beg + q;
    for (; i + 4 < end; i += 8) {
        int2 e0 = edges[i];
        int2 e1 = edges[i + 4];
        bf16x8_t v0 = *(const bf16x8_t*)(Sbf + (size_t)e0.x * DIM + l16 * 8);
        bf16x8_t v1 = *(const bf16x8_t*)(Sbf + (size_t)e1.x * DIM + l16 * 8);
        float n0 = __int_as_float(e0.y);
        float n1 = __int_as_float(e1.y);
        #pragma unroll
        for (int j = 0; j < 8; j++) acc[j] += n0 * bf2f(v0[j]);
        #pragma unroll
        for (int j = 0; j < 8; j++) acc[j] += n1 * bf2f(v1[j]);
    }
    for (; i < end; i += 4) {
        int2 e = edges[i];
        bf16x8_t v = *(const bf16x8_t*)(Sbf + (size_t)e.x * DIM + l16 * 8);
        float nv = __int_as_float(e.y);
        #pragma unroll
        for (int j = 0; j < 8; j++) acc[j] += nv * bf2f(v[j]);
    }

    #pragma unroll
    for (int j = 0; j < 8; j++) {
        acc[j] += __shfl_xor(acc[j], 16, 64);
        acc[j] += __shfl_xor(acc[j], 32, 64);
    }
    if (q == 0) {
        if (do_relu) {
            #pragma unroll
            for (int j = 0; j < 8; j++) acc[j] = fmaxf(acc[j], 0.f);
        }
        float4 o0 = make_float4(acc[0], acc[1], acc[2], acc[3]);
        float4 o1 = make_float4(acc[4], acc[5], acc[6], acc[7]);
        float* row = out + (size_t)node * DIM + l16 * 8;
        *(float4*)row       = o0;
        *(float4*)(row + 4) = o1;
    }
}

// ---------------- launch ----------------

extern "C" void kernel_launch(void* const* d_in, const int* in_sizes, int n_in,
                              void* d_out, int out_size, void* d_ws, size_t ws_size,
                              hipStream_t stream) {
    const float* X    = (const float*)d_in[0];
    const float* W0   = (const float*)d_in[1];
    const float* W1   = (const float*)d_in[2];
    const float* norm = (const float*)d_in[3];
    const int*   src  = (const int*)d_in[4];
    const int*   dst  = (const int*)d_in[5];

    const int N = in_sizes[0] / DIM;   // 50000
    const int E = in_sizes[3];         // 800000

    float* Z = (float*)d_out;
    float* H = (float*)d_out + (size_t)N * DIM;

    // workspace layout (~26 MB)
    char* ws = (char*)d_ws;
    short* Sbf    = (short*)ws;                      // 12.8 MB
    size_t off    = (size_t)N * DIM * sizeof(short);
    short* Wbf0   = (short*)(ws + off); off += DIM * DIM * sizeof(short);
    short* Wbf1   = (short*)(ws + off); off += DIM * DIM * sizeof(short);
    int*   offs   = (int*)(ws + off); off += ((size_t)(N + 1) * 4 + 255) / 256 * 256;
    int*   bcount = (int*)(ws + off); off += 1024;
    int*   boffs  = (int*)(ws + off); off += 1024;
    int*   bcursor= (int*)(ws + off); off += 1024;
    int2*  binned = (int2*)(ws + off); off += (size_t)E * 8;
    int2*  edges  = (int2*)(ws + off); off += (size_t)E * 8;

    // ---- W -> bf16 (independent of CSR chain) ----
    cvt_f32_bf16<<<(DIM * DIM + 2047) / 2048, 256, 0, stream>>>(W0, Wbf0, DIM * DIM);
    cvt_f32_bf16<<<(DIM * DIM + 2047) / 2048, 256, 0, stream>>>(W1, Wbf1, DIM * DIM);

    // ---- CSR build via bucket sort ----
    hipMemsetAsync(bcount, 0, NB * sizeof(int), stream);
    bucket_count<<<(E / 4 + 255) / 256, 256, 0, stream>>>(dst, bcount, E);
    bucket_scan<<<1, 256, 0, stream>>>(bcount, boffs, bcursor);
    bucket_scatter<<<(E + 256 * SC_VPT - 1) / (256 * SC_VPT), 256, 0, stream>>>(
        src, dst, norm, bcursor, binned, E);
    bucket_csr<<<NB, 1024, 0, stream>>>(binned, boffs, offs, edges, N);

    const int gemm_grid = (N + 63) / 64;
    const int prop_grid = (N + 3) / 4;

    // ---- layer 1 ----
    gemm_mfma<<<gemm_grid, 256, 0, stream>>>(X, Wbf0, Sbf, N);
    propagate_kernel<<<prop_grid, 256, 0, stream>>>(Sbf, offs, edges, H, N, 1);

    // ---- layer 2 ----
    gemm_mfma<<<gemm_grid, 256, 0, stream>>>(H, Wbf1, Sbf, N);
    propagate_kernel<<<prop_grid, 256, 0, stream>>>(Sbf, offs, edges, Z, N, 0);
}

// Round 5
// 229.997 us; speedup vs baseline: 2.2187x; 1.0329x over previous
//
#include <hip/hip_runtime.h>

#define DIM 128
#define NB 196            // ceil(50000/256) dst-buckets of 256 nodes
#define BCAP 6144         // fixed bucket capacity (mean 4096, +32 sigma)

typedef __attribute__((ext_vector_type(8))) short bf16x8_t;
typedef __attribute__((ext_vector_type(4))) float f32x4_t;

__device__ __forceinline__ short f2bf(float f) {
    unsigned u = __float_as_uint(f);
    u += 0x7FFFu + ((u >> 16) & 1u);        // round-to-nearest-even
    return (short)(u >> 16);
}
__device__ __forceinline__ float bf2f(short s) {
    return __uint_as_float(((unsigned)(unsigned short)s) << 16);
}
__device__ __forceinline__ int2 ldnt_edge(const int2* p) {
    long long v = __builtin_nontemporal_load((const long long*)p);
    return make_int2((int)(unsigned)(v & 0xffffffffLL), (int)(v >> 32));
}

// ---------------- W0,W1 -> bf16 (one dispatch; Wbf is contiguous 2*DIM*DIM) ----
__global__ void cvt_w_bf16(const float* __restrict__ W0, const float* __restrict__ W1,
                           short* __restrict__ Wbf) {
    int i = (blockIdx.x * 256 + threadIdx.x) * 8;     // grid covers 2*DIM*DIM
    const float* in = (i < DIM * DIM) ? (W0 + i) : (W1 + (i - DIM * DIM));
    float4 a = *(const float4*)in;
    float4 b = *(const float4*)(in + 4);
    bf16x8_t o;
    o[0] = f2bf(a.x); o[1] = f2bf(a.y); o[2] = f2bf(a.z); o[3] = f2bf(a.w);
    o[4] = f2bf(b.x); o[5] = f2bf(b.y); o[6] = f2bf(b.z); o[7] = f2bf(b.w);
    *(bf16x8_t*)(Wbf + i) = o;
}

// ---------------- CSR build: two-level bucket sort (fixed-cap buckets) ----------
// Stage 1: bin edges into bucket regions at bkt*BCAP. One atomic per bucket per
// block claims a compact chunk -> stores land in the block's own footprint.
// binned.x packs (dst&255)<<24 | src  (src < 2^24), binned.y = norm bits.
#define SC_VPT 16
__global__ __launch_bounds__(256) void bucket_scatter(const int* __restrict__ src,
                                                      const int* __restrict__ dst,
                                                      const float* __restrict__ norm,
                                                      int* __restrict__ bcursor,
                                                      int2* __restrict__ binned, int E) {
    __shared__ int hist[NB];
    __shared__ int base[NB];
    int t = threadIdx.x;
    for (int b = t; b < NB; b += 256) hist[b] = 0;
    __syncthreads();

    int e0 = blockIdx.x * (256 * SC_VPT);
    int bkts[SC_VPT];
    int pack[SC_VPT];
    int nrm[SC_VPT];
    #pragma unroll
    for (int k = 0; k < SC_VPT; k++) {
        int e = e0 + k * 256 + t;               // coalesced strided reads
        if (e < E) {
            int d = dst[e];
            bkts[k] = d >> 8;
            pack[k] = ((d & 255) << 24) | src[e];
            nrm[k]  = __float_as_int(norm[e]);
            atomicAdd(&hist[bkts[k]], 1);
        } else bkts[k] = -1;
    }
    __syncthreads();
    for (int b = t; b < NB; b += 256) {
        int c = hist[b];
        base[b] = b * BCAP + (c ? atomicAdd(&bcursor[b], c) : 0);
        hist[b] = 0;
    }
    __syncthreads();
    #pragma unroll
    for (int k = 0; k < SC_VPT; k++) {
        if (bkts[k] >= 0) {
            int pos = base[bkts[k]] + atomicAdd(&hist[bkts[k]], 1);
            binned[pos] = make_int2(pack[k], nrm[k]);
        }
    }
}

// Stage 2: exclusive scan of NB (<256) bucket counts (= post-scatter cursors)
// -> compact global bucket offsets boffs[0..NB].
__global__ __launch_bounds__(256) void bucket_scan(const int* __restrict__ bcount,
                                                   int* __restrict__ boffs) {
    __shared__ int ws_[4];
    int t = threadIdx.x;
    int v = (t < NB) ? bcount[t] : 0;
    int lane = t & 63, w = t >> 6;
    int s = v;
    #pragma unroll
    for (int o = 1; o < 64; o <<= 1) { int x = __shfl_up(s, o, 64); if (lane >= o) s += x; }
    if (lane == 63) ws_[w] = s;
    __syncthreads();
    int wpref = 0;
    for (int k = 0; k < w; k++) wpref += ws_[k];
    int incl = wpref + s;
    if (t < NB) boffs[t] = incl - v;
    if (t == 255) boffs[NB] = incl;
}

// Stage 3: one block per bucket. Counting-sort by dst&255 into the final compact
// CSR segment, emit per-node offs.
__global__ __launch_bounds__(1024) void bucket_csr(const int2* __restrict__ binned,
                                                   const int* __restrict__ boffs,
                                                   int* __restrict__ offs,
                                                   int2* __restrict__ edges, int n) {
    __shared__ int hist[256];
    __shared__ int ws_[4];
    int b    = blockIdx.x;
    int beg  = boffs[b];                 // compact output base
    int cnt  = boffs[b + 1] - beg;
    int ibase= b * BCAP;                 // strided input base
    int t    = threadIdx.x;
    if (t < 256) hist[t] = 0;
    __syncthreads();
    for (int i = t; i < cnt; i += 1024)
        atomicAdd(&hist[(unsigned)binned[ibase + i].x >> 24], 1);
    __syncthreads();
    int v = (t < 256) ? hist[t] : 0;
    int lane = t & 63, w = t >> 6;
    int s = v;
    #pragma unroll
    for (int o = 1; o < 64; o <<= 1) { int x = __shfl_up(s, o, 64); if (lane >= o) s += x; }
    if (t < 256 && lane == 63) ws_[w] = s;
    __syncthreads();
    int wpref = 0;
    if (t < 256) for (int k = 0; k < w; k++) wpref += ws_[k];
    int excl = wpref + s - v;
    __syncthreads();
    if (t < 256) {
        hist[t] = beg + excl;                   // becomes per-node cursor
        int idx = b * 256 + t;
        if (idx <= n) offs[idx] = beg + excl;   // idx==n -> E
    }
    __syncthreads();
    for (int i = t; i < cnt; i += 1024) {
        int2 pr = binned[ibase + i];
        unsigned p = (unsigned)pr.x;
        int pos = atomicAdd(&hist[p >> 24], 1);
        edges[pos] = make_int2((int)(p & 0xFFFFFF), pr.y);
    }
}

// ---------------- GEMM (bf16 MFMA): Cbf[n][128] = bf16( A[n][128] @ Wbf^T )

__global__ __launch_bounds__(256) void gemm_mfma(const float* __restrict__ A,
                                                 const short* __restrict__ Wbf,
                                                 short* __restrict__ Cbf, int n) {
    int wave = threadIdx.x >> 6;
    int lane = threadIdx.x & 63;
    int l16  = lane & 15;
    int quad = lane >> 4;
    int r0 = blockIdx.x * 64 + wave * 16;

    int arow = r0 + l16;
    if (arow >= n) arow = n - 1;               // clamp: OOB rows never stored
    const float* Ar = A + (size_t)arow * DIM + quad * 8;

    bf16x8_t fa[4];
    #pragma unroll
    for (int kk = 0; kk < 4; kk++) {
        float4 x0 = *(const float4*)(Ar + kk * 32);
        float4 x1 = *(const float4*)(Ar + kk * 32 + 4);
        bf16x8_t f;
        f[0] = f2bf(x0.x); f[1] = f2bf(x0.y); f[2] = f2bf(x0.z); f[3] = f2bf(x0.w);
        f[4] = f2bf(x1.x); f[5] = f2bf(x1.y); f[6] = f2bf(x1.z); f[7] = f2bf(x1.w);
        fa[kk] = f;
    }

    #pragma unroll
    for (int ct = 0; ct < 8; ct++) {
        const short* Wr = Wbf + (size_t)(ct * 16 + l16) * DIM + quad * 8;
        f32x4_t acc = {0.f, 0.f, 0.f, 0.f};
        #pragma unroll
        for (int kk = 0; kk < 4; kk++) {
            bf16x8_t fb = *(const bf16x8_t*)(Wr + kk * 32);
            acc = __builtin_amdgcn_mfma_f32_16x16x32_bf16(fa[kk], fb, acc, 0, 0, 0);
        }
        #pragma unroll
        for (int j = 0; j < 4; j++) {
            int row = r0 + quad * 4 + j;
            if (row < n) Cbf[(size_t)row * DIM + ct * 16 + l16] = f2bf(acc[j]);
        }
    }
}

// ---------------- Propagate: out[v] = sum_{e: dst=v} Sbf[src[e]] * norm[e]
// One wave per node; quarter-wave (16 lanes) covers a 256B bf16 row.
// 4 quarter-streams x unroll-4 -> 16 independent row-gathers in flight/wave.
// Edge reads + output writes are non-temporal (single-use; keep L2 for Sbf).

__global__ __launch_bounds__(256) void propagate_kernel(const short* __restrict__ Sbf,
                                                        const int* __restrict__ offs,
                                                        const int2* __restrict__ edges,
                                                        float* __restrict__ out,
                                                        int n, int do_relu) {
    int node = blockIdx.x * 4 + (threadIdx.x >> 6);
    if (node >= n) return;
    int lane = threadIdx.x & 63;
    int q   = lane >> 4;
    int l16 = lane & 15;
    int beg = offs[node];
    int end = offs[node + 1];

    float acc[8] = {};
    int i = beg + q;
    for (; i + 12 < end; i += 16) {
        int2 e0 = ldnt_edge(&edges[i]);
        int2 e1 = ldnt_edge(&edges[i + 4]);
        int2 e2 = ldnt_edge(&edges[i + 8]);
        int2 e3 = ldnt_edge(&edges[i + 12]);
        bf16x8_t v0 = *(const bf16x8_t*)(Sbf + (size_t)e0.x * DIM + l16 * 8);
        bf16x8_t v1 = *(const bf16x8_t*)(Sbf + (size_t)e1.x * DIM + l16 * 8);
        bf16x8_t v2 = *(const bf16x8_t*)(Sbf + (size_t)e2.x * DIM + l16 * 8);
        bf16x8_t v3 = *(const bf16x8_t*)(Sbf + (size_t)e3.x * DIM + l16 * 8);
        float n0 = __int_as_float(e0.y);
        float n1 = __int_as_float(e1.y);
        float n2 = __int_as_float(e2.y);
        float n3 = __int_as_float(e3.y);
        #pragma unroll
        for (int j = 0; j < 8; j++) acc[j] += n0 * bf2f(v0[j]);
        #pragma unroll
        for (int j = 0; j < 8; j++) acc[j] += n1 * bf2f(v1[j]);
        #pragma unroll
        for (int j = 0; j < 8; j++) acc[j] += n2 * bf2f(v2[j]);
        #pragma unroll
        for (int j = 0; j < 8; j++) acc[j] += n3 * bf2f(v3[j]);
    }
    for (; i < end; i += 4) {
        int2 e = ldnt_edge(&edges[i]);
        bf16x8_t v = *(const bf16x8_t*)(Sbf + (size_t)e.x * DIM + l16 * 8);
        float nv = __int_as_float(e.y);
        #pragma unroll
        for (int j = 0; j < 8; j++) acc[j] += nv * bf2f(v[j]);
    }

    #pragma unroll
    for (int j = 0; j < 8; j++) {
        acc[j] += __shfl_xor(acc[j], 16, 64);
        acc[j] += __shfl_xor(acc[j], 32, 64);
    }
    if (q == 0) {
        if (do_relu) {
            #pragma unroll
            for (int j = 0; j < 8; j++) acc[j] = fmaxf(acc[j], 0.f);
        }
        f32x4_t o0 = {acc[0], acc[1], acc[2], acc[3]};
        f32x4_t o1 = {acc[4], acc[5], acc[6], acc[7]};
        float* row = out + (size_t)node * DIM + l16 * 8;
        __builtin_nontemporal_store(o0, (f32x4_t*)row);
        __builtin_nontemporal_store(o1, (f32x4_t*)(row + 4));
    }
}

// ---------------- launch ----------------

extern "C" void kernel_launch(void* const* d_in, const int* in_sizes, int n_in,
                              void* d_out, int out_size, void* d_ws, size_t ws_size,
                              hipStream_t stream) {
    const float* X    = (const float*)d_in[0];
    const float* W0   = (const float*)d_in[1];
    const float* W1   = (const float*)d_in[2];
    const float* norm = (const float*)d_in[3];
    const int*   src  = (const int*)d_in[4];
    const int*   dst  = (const int*)d_in[5];

    const int N = in_sizes[0] / DIM;   // 50000
    const int E = in_sizes[3];         // 800000

    float* Z = (float*)d_out;
    float* H = (float*)d_out + (size_t)N * DIM;

    // workspace layout (~29 MB)
    char* ws = (char*)d_ws;
    short* Sbf    = (short*)ws;                      // 12.8 MB
    size_t off    = (size_t)N * DIM * sizeof(short);
    short* Wbf0   = (short*)(ws + off); off += 2 * DIM * DIM * sizeof(short);
    short* Wbf1   = Wbf0 + DIM * DIM;
    int*   offs   = (int*)(ws + off); off += ((size_t)(N + 1) * 4 + 255) / 256 * 256;
    int*   bcursor= (int*)(ws + off); off += 1024;
    int*   boffs  = (int*)(ws + off); off += 1024;
    int2*  binned = (int2*)(ws + off); off += (size_t)NB * BCAP * 8;
    int2*  edges  = (int2*)(ws + off); off += (size_t)E * 8;

    // ---- W -> bf16 (independent of CSR chain) ----
    cvt_w_bf16<<<(2 * DIM * DIM) / (256 * 8), 256, 0, stream>>>(W0, W1, Wbf0);

    // ---- CSR build via fixed-capacity bucket sort ----
    hipMemsetAsync(bcursor, 0, NB * sizeof(int), stream);
    bucket_scatter<<<(E + 256 * SC_VPT - 1) / (256 * SC_VPT), 256, 0, stream>>>(
        src, dst, norm, bcursor, binned, E);
    bucket_scan<<<1, 256, 0, stream>>>(bcursor, boffs);
    bucket_csr<<<NB, 1024, 0, stream>>>(binned, boffs, offs, edges, N);

    const int gemm_grid = (N + 63) / 64;
    const int prop_grid = (N + 3) / 4;

    // ---- layer 1 ----
    gemm_mfma<<<gemm_grid, 256, 0, stream>>>(X, Wbf0, Sbf, N);
    propagate_kernel<<<prop_grid, 256, 0, stream>>>(Sbf, offs, edges, H, N, 1);

    // ---- layer 2 ----
    gemm_mfma<<<gemm_grid, 256, 0, stream>>>(H, Wbf1, Sbf, N);
    propagate_kernel<<<prop_grid, 256, 0, stream>>>(Sbf, offs, edges, Z, N, 0);
}